// Round 5
// baseline (126.188 us; speedup 1.0000x reference)
//
#include <hip/hip_runtime.h>
#include <hip/hip_bf16.h>
#include <math.h>

#define N_TOT   16384
#define M_EV    4096
#define IN_DIM  128
#define SPACE_D 4
#define PROP_D  64
#define K_NN    32
#define ROWS_W  4               // query rows per wave
#define CAND_CAP 64             // candidate slots per row (1/lane)

// ---------------------------------------------------------------------------
// Kernel 1: space = x @ Ws + bs ; prop = x @ Wp + bp
// ---------------------------------------------------------------------------
__global__ __launch_bounds__(256) void linear_kernel(
    const float* __restrict__ x,
    const float* __restrict__ Ws, const float* __restrict__ bs,
    const float* __restrict__ Wp, const float* __restrict__ bp,
    float* __restrict__ space, float* __restrict__ prop)
{
  const int lane = threadIdx.x & 63;
  const int wid  = threadIdx.x >> 6;
  const int r0   = __builtin_amdgcn_readfirstlane((int)blockIdx.x * 16 + wid * 4);

  const float* xr = x + (size_t)r0 * IN_DIM;

  float a0 = bp[lane];
  float a1 = a0, a2 = a0, a3 = a0;
  #pragma unroll
  for (int i = 0; i < IN_DIM; ++i) {
    const float w = Wp[i * PROP_D + lane];
    a0 = fmaf(xr[i],              w, a0);
    a1 = fmaf(xr[IN_DIM + i],     w, a1);
    a2 = fmaf(xr[2 * IN_DIM + i], w, a2);
    a3 = fmaf(xr[3 * IN_DIM + i], w, a3);
  }
  prop[(size_t)(r0 + 0) * PROP_D + lane] = a0;
  prop[(size_t)(r0 + 1) * PROP_D + lane] = a1;
  prop[(size_t)(r0 + 2) * PROP_D + lane] = a2;
  prop[(size_t)(r0 + 3) * PROP_D + lane] = a3;

  if (lane < 16) {
    const int r = lane >> 2, c = lane & 3;
    const float* xq = x + (size_t)(r0 + r) * IN_DIM;
    float a = bs[c];
    #pragma unroll
    for (int i = 0; i < IN_DIM; ++i)
      a = fmaf(xq[i], Ws[i * SPACE_D + c], a);
    space[(size_t)(r0 + r) * SPACE_D + c] = a;
  }
}

// per-lane count of set bits of mk strictly below this lane
__device__ __forceinline__ int mbcnt64(unsigned long long mk) {
  return (int)__builtin_amdgcn_mbcnt_hi((unsigned)(mk >> 32),
           __builtin_amdgcn_mbcnt_lo((unsigned)mk, 0u));
}

// ---------------------------------------------------------------------------
// Kernel 2: per-row exact KNN (K=32 of 4096) + weighted aggregation.
// 512 threads = 8 waves; each wave owns 4 consecutive rows (32 rows/block).
// Slab (64 KB) in LDS; candidate float4 loaded ONCE per wave per candidate
// and reused for 4 rows. Distances in expanded form d = q2 + c2 - 2 q.c
// (c2 shared across rows). Pass A: per-lane running min per row; bitonic
// sort of lane-mins -> Tub[r]. Pass B: recompute + ballot-compact survivors
// (<= 64 w.p. ~99.3%; exact fallback otherwise). Tail: bisect on 1 val/lane,
// stable (lowest-index) tie handling; winners overlay the candidate buffer.
// ---------------------------------------------------------------------------
__global__ __launch_bounds__(512) void knn_kernel(
    const float4* __restrict__ space,   // [N_TOT]
    const float*  __restrict__ prop,    // [N_TOT * PROP_D]
    float*        __restrict__ out)     // [N_TOT * 2*PROP_D]
{
  const int lane = threadIdx.x & 63;
  const int wid  = threadIdx.x >> 6;              // 0..7
  const int rb0  = wid * ROWS_W;                  // row-in-block base (0..28)
  const int row0 = (int)blockIdx.x * 32 + rb0;    // first of 4 rows
  const int m0   = row0 & ~(M_EV - 1);            // event base
  const int ml0  = row0 & (M_EV - 1);             // local index of row0

  __shared__ float4 s_sp[M_EV];                   // 64 KB
  __shared__ uint2  s_cand[32][CAND_CAP];         // 16 KB {idx, bits}

  // stage event slab: 4096 float4 by 512 threads
  {
    const float4* src = space + m0;
    #pragma unroll
    for (int t = 0; t < 8; ++t) {
      const int i = (int)threadIdx.x + t * 512;
      s_sp[i] = src[i];
    }
  }
  __syncthreads();

  // per-row query params: -2q and q2
  float mqx[ROWS_W], mqy[ROWS_W], mqz[ROWS_W], mqw[ROWS_W], q2[ROWS_W];
  #pragma unroll
  for (int r = 0; r < ROWS_W; ++r) {
    const float4 q = s_sp[ml0 + r];
    mqx[r] = -2.f * q.x; mqy[r] = -2.f * q.y;
    mqz[r] = -2.f * q.z; mqw[r] = -2.f * q.w;
    q2[r]  = fmaf(q.x, q.x, fmaf(q.y, q.y, fmaf(q.z, q.z, q.w * q.w)));
  }

  // --- pass A: per-lane running min per row (no arrays spanning passes) ---
  float mn[ROWS_W];
  #pragma unroll
  for (int r = 0; r < ROWS_W; ++r) mn[r] = INFINITY;
  #pragma unroll
  for (int t = 0; t < 64; ++t) {
    const float4 c = s_sp[lane + (t << 6)];
    const float c2 = fmaf(c.x, c.x, fmaf(c.y, c.y, fmaf(c.z, c.z, c.w * c.w)));
    #pragma unroll
    for (int r = 0; r < ROWS_W; ++r) {
      const float d = fmaf(mqx[r], c.x, fmaf(mqy[r], c.y,
                      fmaf(mqz[r], c.z, fmaf(mqw[r], c.w, q2[r] + c2))));
      mn[r] = fminf(mn[r], d);
    }
  }

  // --- bitonic sort of lane minima per row -> Tub[r] (32nd smallest) ---
  float Tub[ROWS_W];
  #pragma unroll
  for (int r = 0; r < ROWS_W; ++r) {
    float ms = mn[r];
    #pragma unroll
    for (int k = 2; k <= 64; k <<= 1) {
      #pragma unroll
      for (int j = k >> 1; j > 0; j >>= 1) {
        const float o = __shfl_xor(ms, j);
        const bool keepmin = (((lane & j) == 0) == ((lane & k) == 0));
        ms = keepmin ? fminf(ms, o) : fmaxf(ms, o);
      }
    }
    Tub[r] = __shfl(ms, 31);
  }

  // --- pass B: recompute + ballot-compact survivors per row ---
  int base[ROWS_W];
  #pragma unroll
  for (int r = 0; r < ROWS_W; ++r) base[r] = 0;
  #pragma unroll
  for (int t = 0; t < 64; ++t) {
    const float4 c = s_sp[lane + (t << 6)];
    const float c2 = fmaf(c.x, c.x, fmaf(c.y, c.y, fmaf(c.z, c.z, c.w * c.w)));
    #pragma unroll
    for (int r = 0; r < ROWS_W; ++r) {
      const float d = fmaf(mqx[r], c.x, fmaf(mqy[r], c.y,
                      fmaf(mqz[r], c.z, fmaf(mqw[r], c.w, q2[r] + c2))));
      const bool p = (d <= Tub[r]);
      const unsigned long long mk = __ballot(p);
      if (p) {
        const int pos = base[r] + mbcnt64(mk);
        if (pos < CAND_CAP)
          s_cand[rb0 + r][pos] = make_uint2((unsigned)((t << 6) + lane),
                                            __float_as_uint(d));
      }
      base[r] += (int)__popcll(mk);
    }
  }

  // --- per-row tail: exact top-32, winners overlay s_cand[rb][0..31] ---
  #pragma unroll
  for (int r = 0; r < ROWS_W; ++r) {
    const int rb = rb0 + r;

    if (base[r] > CAND_CAP) {
      // ---- cold exact fallback (wave-uniform branch): bisect + compact ----
      unsigned lo = 0u, hi = __float_as_uint(Tub[r]);
      while (lo < hi) {
        const unsigned mid = (lo + hi) >> 1;
        const float fm = __uint_as_float(mid);
        int c = 0;
        #pragma unroll 1
        for (int t = 0; t < 64; ++t) {
          const float4 cc = s_sp[lane + (t << 6)];
          const float c2 = fmaf(cc.x, cc.x, fmaf(cc.y, cc.y, fmaf(cc.z, cc.z, cc.w * cc.w)));
          const float d = fmaf(mqx[r], cc.x, fmaf(mqy[r], cc.y,
                          fmaf(mqz[r], cc.z, fmaf(mqw[r], cc.w, q2[r] + c2))));
          c += (int)__popcll(__ballot(d <= fm));
        }
        if (c >= K_NN) { hi = mid; if (c == K_NN) break; }
        else lo = mid + 1;
      }
      const float T = __uint_as_float(hi);
      int cnt = 0;
      #pragma unroll 1
      for (int pass = 0; pass < 2; ++pass) {
        #pragma unroll 1
        for (int t = 0; t < 64; ++t) {
          const float4 cc = s_sp[lane + (t << 6)];
          const float c2 = fmaf(cc.x, cc.x, fmaf(cc.y, cc.y, fmaf(cc.z, cc.z, cc.w * cc.w)));
          const float d = fmaf(mqx[r], cc.x, fmaf(mqy[r], cc.y,
                          fmaf(mqz[r], cc.z, fmaf(mqw[r], cc.w, q2[r] + c2))));
          const bool p = pass ? (d == T) : (d < T);
          const unsigned long long mk = __ballot(p);
          if (p) {
            const int pos = cnt + mbcnt64(mk);
            if (pos < K_NN)
              s_cand[rb][pos] = make_uint2((unsigned)((t << 6) + lane),
                       __float_as_uint(__expf(-10.f * fmaxf(d, 0.f))));
          }
          cnt += (int)__popcll(mk);
        }
        if (cnt >= K_NN) break;
      }
    } else {
      // ---- hot tail: bisect on 1 value/lane among C = base[r] ----
      const int C = base[r];
      const uint2 cv = s_cand[rb][lane];
      const bool h = lane < C;
      const float v = h ? __uint_as_float(cv.y) : INFINITY;

      unsigned lo = 0u, hi = __float_as_uint(Tub[r]);
      while (lo < hi) {
        const unsigned mid = (lo + hi) >> 1;
        const int c = (int)__popcll(__ballot(v <= __uint_as_float(mid)));
        if (c >= K_NN) { hi = mid; if (c == K_NN) break; }
        else lo = mid + 1;
      }
      const float T2 = __uint_as_float(hi);

      // stable selection: strict-less, then lowest-position equals
      const unsigned long long mkE = __ballot(v == T2);
      const int L = (int)__popcll(__ballot(v < T2));
      const bool sel = (v < T2) || ((v == T2) && (mbcnt64(mkE) < K_NN - L));

      const unsigned long long mkS = __ballot(sel);
      if (sel) {
        const int pos = mbcnt64(mkS);
        const float w = __expf(-10.f * fmaxf(v, 0.f));
        s_cand[rb][pos] = make_uint2(cv.x, __float_as_uint(w));
      }
    }
  }

  // --- aggregation: lane = feature, 32 winners per row ---
  const float* __restrict__ pb = prop + ((size_t)m0 << 6) + lane;
  #pragma unroll
  for (int r = 0; r < ROWS_W; ++r) {
    const int rb = rb0 + r;
    float accm = 0.f;
    float accx = -INFINITY;
    #pragma unroll 8
    for (int n = 0; n < K_NN; ++n) {
      const uint2 e = s_cand[rb][n];              // uniform LDS broadcast
      const float w = __uint_as_float(e.y);
      const float v = pb[(size_t)e.x << 6];       // coalesced 256B, L2-hot
      const float wv = w * v;
      accm += wv;
      accx = fmaxf(accx, wv);
    }
    const int row = row0 + r;
    out[(size_t)row * 128 + lane]      = accm * (1.f / K_NN);
    out[(size_t)row * 128 + 64 + lane] = accx;
  }
}

// ---------------------------------------------------------------------------
extern "C" void kernel_launch(void* const* d_in, const int* in_sizes, int n_in,
                              void* d_out, int out_size, void* d_ws, size_t ws_size,
                              hipStream_t stream) {
  const float* x  = (const float*)d_in[0];
  const float* Ws = (const float*)d_in[1];
  const float* bs = (const float*)d_in[2];
  const float* Wp = (const float*)d_in[3];
  const float* bp = (const float*)d_in[4];
  float* out = (float*)d_out;

  // workspace layout: prop [N,64] f32 (4 MB) | space [N,4] f32 (256 KB)
  float* prop  = (float*)d_ws;
  float* space = (float*)((char*)d_ws + (size_t)N_TOT * PROP_D * sizeof(float));

  linear_kernel<<<N_TOT / 16, 256, 0, stream>>>(x, Ws, bs, Wp, bp, space, prop);
  knn_kernel<<<N_TOT / 32, 512, 0, stream>>>((const float4*)space, prop, out);
}

// Round 6
// 67.667 us; speedup vs baseline: 1.8648x; 1.8648x over previous
//
#include <hip/hip_runtime.h>
#include <hip/hip_bf16.h>
#include <math.h>

#define N_TOT   16384
#define M_EV    4096
#define IN_DIM  128
#define SPACE_D 4
#define PROP_D  64
#define K_NN    32
#define CAND_CAP 128            // survivor slots per row (2/lane)
#define MARGIN  0.04f           // covers worst-case f16 approx error (~0.02)

typedef _Float16 h2 __attribute__((ext_vector_type(2)));

__device__ __forceinline__ float fdot2f(h2 a, h2 b, float c) {
#if __has_builtin(__builtin_amdgcn_fdot2)
  return __builtin_amdgcn_fdot2(a, b, c, false);   // v_dot2_f32_f16
#else
  return fmaf((float)a.x, (float)b.x, fmaf((float)a.y, (float)b.y, c));
#endif
}

// ---------------------------------------------------------------------------
// Kernel 1: space = x @ Ws + bs ; prop = x @ Wp + bp
// ---------------------------------------------------------------------------
__global__ __launch_bounds__(256) void linear_kernel(
    const float* __restrict__ x,
    const float* __restrict__ Ws, const float* __restrict__ bs,
    const float* __restrict__ Wp, const float* __restrict__ bp,
    float* __restrict__ space, float* __restrict__ prop)
{
  const int lane = threadIdx.x & 63;
  const int wid  = threadIdx.x >> 6;
  const int r0   = __builtin_amdgcn_readfirstlane((int)blockIdx.x * 16 + wid * 4);

  const float* xr = x + (size_t)r0 * IN_DIM;

  float a0 = bp[lane];
  float a1 = a0, a2 = a0, a3 = a0;
  #pragma unroll
  for (int i = 0; i < IN_DIM; ++i) {
    const float w = Wp[i * PROP_D + lane];
    a0 = fmaf(xr[i],              w, a0);
    a1 = fmaf(xr[IN_DIM + i],     w, a1);
    a2 = fmaf(xr[2 * IN_DIM + i], w, a2);
    a3 = fmaf(xr[3 * IN_DIM + i], w, a3);
  }
  prop[(size_t)(r0 + 0) * PROP_D + lane] = a0;
  prop[(size_t)(r0 + 1) * PROP_D + lane] = a1;
  prop[(size_t)(r0 + 2) * PROP_D + lane] = a2;
  prop[(size_t)(r0 + 3) * PROP_D + lane] = a3;

  if (lane < 16) {
    const int r = lane >> 2, c = lane & 3;
    const float* xq = x + (size_t)(r0 + r) * IN_DIM;
    float a = bs[c];
    #pragma unroll
    for (int i = 0; i < IN_DIM; ++i)
      a = fmaf(xq[i], Ws[i * SPACE_D + c], a);
    space[(size_t)(r0 + r) * SPACE_D + c] = a;
  }
}

// per-lane count of set bits of mk strictly below this lane
__device__ __forceinline__ int mbcnt64(unsigned long long mk) {
  return (int)__builtin_amdgcn_mbcnt_hi((unsigned)(mk >> 32),
           __builtin_amdgcn_mbcnt_lo((unsigned)mk, 0u));
}

// ---------------------------------------------------------------------------
// Kernel 2: per-row exact KNN (K=32 of 4096) + weighted aggregation.
// 512 threads = 8 waves = 8 rows. Slab packed f16x4 in LDS (32 KB).
// Pass A: approx dist via v_dot2_f32_f16 (5 VALU/cand), running lane-min.
// Bitonic-sort lane mins -> Tub; T = Tub + MARGIN (covers f16 error).
// Pass B: recompute approx, ballot-append survivor IDX only (<=128).
// Refine: exact f32 distance for <=2 survivors/lane from global space;
// exact bisect + stable tie select (lowest index) -> identical set to f32 ref.
// ---------------------------------------------------------------------------
__global__ __launch_bounds__(512, 6) void knn_kernel(
    const float4* __restrict__ space,   // [N_TOT] f32 coords
    const float*  __restrict__ prop,    // [N_TOT * PROP_D]
    float*        __restrict__ out)     // [N_TOT * 2*PROP_D]
{
  const int lane = threadIdx.x & 63;
  const int wid  = threadIdx.x >> 6;              // 0..7
  const int row  = (int)blockIdx.x * 8 + wid;     // 1 wave = 1 row
  const int m0   = row & ~(M_EV - 1);
  const int mloc = row & (M_EV - 1);

  __shared__ uint2 s_h[M_EV];                     // 32 KB packed f16x4
  __shared__ int   s_ci[8][CAND_CAP];             // 4 KB survivor indices
  __shared__ uint2 s_w[8][K_NN];                  // 2 KB winners {idx, wbits}

  // stage: f32 -> packed f16x4
  {
    const float4* src = space + m0;
    #pragma unroll
    for (int t = 0; t < 8; ++t) {
      const int i = (int)threadIdx.x + t * 512;
      const float4 c = src[i];
      h2 a; a.x = (_Float16)c.x; a.y = (_Float16)c.y;
      h2 b; b.x = (_Float16)c.z; b.y = (_Float16)c.w;
      s_h[i] = make_uint2(__builtin_bit_cast(unsigned, a),
                          __builtin_bit_cast(unsigned, b));
    }
  }
  __syncthreads();

  const uint2 qh = s_h[mloc];                     // wave-uniform
  const h2 q01 = __builtin_bit_cast(h2, qh.x);
  const h2 q23 = __builtin_bit_cast(h2, qh.y);

  // --- pass A: approx distances, running per-lane min ---
  float mn = INFINITY;
  #pragma unroll
  for (int t = 0; t < 64; ++t) {
    const uint2 u = s_h[lane + (t << 6)];
    const h2 d01 = q01 - __builtin_bit_cast(h2, u.x);
    const h2 d23 = q23 - __builtin_bit_cast(h2, u.y);
    const float e = fdot2f(d01, d01, fdot2f(d23, d23, 0.f));
    mn = fminf(mn, e);
  }

  // --- bitonic sort of lane minima (ascending) -> Tub (32nd smallest) ---
  float ms = mn;
  #pragma unroll
  for (int k = 2; k <= 64; k <<= 1) {
    #pragma unroll
    for (int j = k >> 1; j > 0; j >>= 1) {
      const float o = __shfl_xor(ms, j);
      const bool keepmin = (((lane & j) == 0) == ((lane & k) == 0));
      ms = keepmin ? fminf(ms, o) : fmaxf(ms, o);
    }
  }
  const float T = __shfl(ms, 31) + MARGIN;        // safe prune threshold

  // --- pass B: recompute approx, ballot-append survivor indices ---
  int C;
  {
    int base = 0;
    #pragma unroll
    for (int t = 0; t < 64; ++t) {
      const uint2 u = s_h[lane + (t << 6)];
      const h2 d01 = q01 - __builtin_bit_cast(h2, u.x);
      const h2 d23 = q23 - __builtin_bit_cast(h2, u.y);
      const float e = fdot2f(d01, d01, fdot2f(d23, d23, 0.f));
      const bool p = (e <= T);
      const unsigned long long mk = __ballot(p);
      if (p) {
        const int pos = base + mbcnt64(mk);
        if (pos < CAND_CAP) s_ci[wid][pos] = (t << 6) + lane;
      }
      base += (int)__popcll(mk);
    }
    C = base;
  }

  // exact query coords (f32, wave-uniform global load, L2-hot)
  const float4 q4 = space[m0 + mloc];

  if (C > CAND_CAP) {
    // --- cold exact fallback (≈1e-5 of rows): bisect exact d from global ---
    const float4* __restrict__ ev = space + m0;
    unsigned lo = 0u, hi = __float_as_uint(T);
    while (lo < hi) {
      const unsigned mid = (lo + hi) >> 1;
      const float fm = __uint_as_float(mid);
      int c = 0;
      #pragma unroll 1
      for (int t = 0; t < 64; ++t) {
        const float4 cc = ev[lane + (t << 6)];
        const float dx = q4.x - cc.x, dy = q4.y - cc.y;
        const float dz = q4.z - cc.z, dw = q4.w - cc.w;
        const float dd = fmaf(dx, dx, fmaf(dy, dy, fmaf(dz, dz, dw * dw)));
        c += (int)__popcll(__ballot(dd <= fm));
      }
      if (c >= K_NN) { hi = mid; if (c == K_NN) break; }
      else lo = mid + 1;
    }
    const float Tf = __uint_as_float(hi);
    int cnt = 0;
    #pragma unroll 1
    for (int pass = 0; pass < 2; ++pass) {        // 0: strict-less, 1: equal
      #pragma unroll 1
      for (int t = 0; t < 64; ++t) {
        const float4 cc = ev[lane + (t << 6)];
        const float dx = q4.x - cc.x, dy = q4.y - cc.y;
        const float dz = q4.z - cc.z, dw = q4.w - cc.w;
        const float dd = fmaf(dx, dx, fmaf(dy, dy, fmaf(dz, dz, dw * dw)));
        const bool p = pass ? (dd == Tf) : (dd < Tf);
        const unsigned long long mk = __ballot(p);
        if (p) {
          const int pos = cnt + mbcnt64(mk);
          if (pos < K_NN) s_ci[wid][pos] = (t << 6) + lane;
        }
        cnt += (int)__popcll(mk);
      }
      if (cnt >= K_NN) break;
    }
    C = K_NN;                                     // exact stable top-32 set
  }

  // --- refine: exact f32 distances for <=2 survivors/lane (global, L2) ---
  const int i0 = (lane < C)      ? s_ci[wid][lane]      : -1;
  const int i1 = (64 + lane < C) ? s_ci[wid][64 + lane] : -1;
  float v0 = INFINITY, v1 = INFINITY;
  if (i0 >= 0) {
    const float4 cc = space[m0 + i0];
    const float dx = q4.x - cc.x, dy = q4.y - cc.y;
    const float dz = q4.z - cc.z, dw = q4.w - cc.w;
    v0 = fmaf(dx, dx, fmaf(dy, dy, fmaf(dz, dz, dw * dw)));
  }
  if (i1 >= 0) {
    const float4 cc = space[m0 + i1];
    const float dx = q4.x - cc.x, dy = q4.y - cc.y;
    const float dz = q4.z - cc.z, dw = q4.w - cc.w;
    v1 = fmaf(dx, dx, fmaf(dy, dy, fmaf(dz, dz, dw * dw)));
  }

  // exact bisect for the 32nd-smallest of {v0,v1} (count(v<=T) >= 32 holds)
  unsigned lo = 0u, hi = __float_as_uint(T);
  while (lo < hi) {
    const unsigned mid = (lo + hi) >> 1;
    const float fm = __uint_as_float(mid);
    const int c = (int)__popcll(__ballot(v0 <= fm)) +
                  (int)__popcll(__ballot(v1 <= fm));
    if (c >= K_NN) { hi = mid; if (c == K_NN) break; }
    else lo = mid + 1;
  }
  const float T2 = __uint_as_float(hi);

  // stable selection: strict-less, then lowest-index equals
  const unsigned long long mkE0 = __ballot(v0 == T2);
  const unsigned long long mkE1 = __ballot(v1 == T2);
  const int L = (int)__popcll(__ballot(v0 < T2)) +
                (int)__popcll(__ballot(v1 < T2));
  const int e = K_NN - L;
  const int nE0 = (int)__popcll(mkE0);
  const bool sel0 = (v0 < T2) || ((v0 == T2) && (mbcnt64(mkE0) < e));
  const bool sel1 = (v1 < T2) || ((v1 == T2) && (nE0 + mbcnt64(mkE1) < e));

  const float w0 = __expf(-10.f * v0);
  const float w1 = __expf(-10.f * v1);

  {
    const unsigned long long mkS0 = __ballot(sel0);
    if (sel0) {
      const int pos = mbcnt64(mkS0);
      s_w[wid][pos] = make_uint2((unsigned)i0, __float_as_uint(w0));
    }
    const int b0 = (int)__popcll(mkS0);
    const unsigned long long mkS1 = __ballot(sel1);
    if (sel1) {
      const int pos = b0 + mbcnt64(mkS1);
      s_w[wid][pos] = make_uint2((unsigned)i1, __float_as_uint(w1));
    }
  }

  // --- aggregation: lane = feature, 32 winners ---
  float accm = 0.f;
  float accx = -INFINITY;
  const float* __restrict__ pb = prop + ((size_t)m0 << 6) + lane;
  #pragma unroll 8
  for (int n = 0; n < K_NN; ++n) {
    const uint2 wn = s_w[wid][n];                 // uniform LDS broadcast
    const float w = __uint_as_float(wn.y);
    const float v = pb[(size_t)wn.x << 6];        // coalesced 256B, L2-hot
    const float wv = w * v;
    accm += wv;
    accx = fmaxf(accx, wv);
  }
  out[(size_t)row * 128 + lane]      = accm * (1.f / K_NN);
  out[(size_t)row * 128 + 64 + lane] = accx;
}

// ---------------------------------------------------------------------------
extern "C" void kernel_launch(void* const* d_in, const int* in_sizes, int n_in,
                              void* d_out, int out_size, void* d_ws, size_t ws_size,
                              hipStream_t stream) {
  const float* x  = (const float*)d_in[0];
  const float* Ws = (const float*)d_in[1];
  const float* bs = (const float*)d_in[2];
  const float* Wp = (const float*)d_in[3];
  const float* bp = (const float*)d_in[4];
  float* out = (float*)d_out;

  // workspace layout: prop [N,64] f32 (4 MB) | space [N,4] f32 (256 KB)
  float* prop  = (float*)d_ws;
  float* space = (float*)((char*)d_ws + (size_t)N_TOT * PROP_D * sizeof(float));

  linear_kernel<<<N_TOT / 16, 256, 0, stream>>>(x, Ws, bs, Wp, bp, space, prop);
  knn_kernel<<<N_TOT / 8, 512, 0, stream>>>((const float4*)space, prop, out);
}

// Round 7
// 61.636 us; speedup vs baseline: 2.0473x; 1.0978x over previous
//
#include <hip/hip_runtime.h>
#include <hip/hip_bf16.h>
#include <math.h>

#define N_TOT   16384
#define M_EV    4096
#define IN_DIM  128
#define SPACE_D 4
#define PROP_D  64
#define K_NN    32
#define CAND_CAP 128            // survivor slots per row (2/lane)
#define MARGIN  0.04f           // covers f16 approx error near threshold

typedef _Float16 h2 __attribute__((ext_vector_type(2)));
typedef unsigned long long u64;

__device__ __forceinline__ h2 pkmin(h2 a, h2 b) {
#if __has_builtin(__builtin_elementwise_min)
  return __builtin_elementwise_min(a, b);
#else
  h2 r; r.x = (a.x < b.x) ? a.x : b.x; r.y = (a.y < b.y) ? a.y : b.y; return r;
#endif
}

__device__ __forceinline__ h2 pkrtz(float a, float b) {
  return __builtin_bit_cast(h2, __builtin_amdgcn_cvt_pkrtz(a, b));
}

// ---------------------------------------------------------------------------
// Kernel 1: space = x @ Ws + bs ; prop = x @ Wp + bp
// ---------------------------------------------------------------------------
__global__ __launch_bounds__(256) void linear_kernel(
    const float* __restrict__ x,
    const float* __restrict__ Ws, const float* __restrict__ bs,
    const float* __restrict__ Wp, const float* __restrict__ bp,
    float* __restrict__ space, float* __restrict__ prop)
{
  const int lane = threadIdx.x & 63;
  const int wid  = threadIdx.x >> 6;
  const int r0   = __builtin_amdgcn_readfirstlane((int)blockIdx.x * 16 + wid * 4);

  const float* xr = x + (size_t)r0 * IN_DIM;

  float a0 = bp[lane];
  float a1 = a0, a2 = a0, a3 = a0;
  #pragma unroll
  for (int i = 0; i < IN_DIM; ++i) {
    const float w = Wp[i * PROP_D + lane];
    a0 = fmaf(xr[i],              w, a0);
    a1 = fmaf(xr[IN_DIM + i],     w, a1);
    a2 = fmaf(xr[2 * IN_DIM + i], w, a2);
    a3 = fmaf(xr[3 * IN_DIM + i], w, a3);
  }
  prop[(size_t)(r0 + 0) * PROP_D + lane] = a0;
  prop[(size_t)(r0 + 1) * PROP_D + lane] = a1;
  prop[(size_t)(r0 + 2) * PROP_D + lane] = a2;
  prop[(size_t)(r0 + 3) * PROP_D + lane] = a3;

  if (lane < 16) {
    const int r = lane >> 2, c = lane & 3;
    const float* xq = x + (size_t)(r0 + r) * IN_DIM;
    float a = bs[c];
    #pragma unroll
    for (int i = 0; i < IN_DIM; ++i)
      a = fmaf(xq[i], Ws[i * SPACE_D + c], a);
    space[(size_t)(r0 + r) * SPACE_D + c] = a;
  }
}

// per-lane count of set bits of mk strictly below this lane
__device__ __forceinline__ int mbcnt64(u64 mk) {
  return (int)__builtin_amdgcn_mbcnt_hi((unsigned)(mk >> 32),
           __builtin_amdgcn_mbcnt_lo((unsigned)mk, 0u));
}

// ---------------------------------------------------------------------------
// Kernel 2: per-row exact KNN (K=32 of 4096) + weighted aggregation.
// 512 threads = 8 waves = 8 rows. Slab pair-packed f16 in LDS (32 KB):
// s_pk[i] = {h2(x_i,x_{i+2048}), h2(y_i,y_{i+2048}), ...} -> one ds_read_b128
// + packed f16 VALU covers TWO candidates. Pass A: running packed lane-min
// (128 partitions) -> Tub via ballot-bisect. Pass B: recompute (bit-identical)
// + LDS-atomic append of survivor indices (order-free). Tail: exact f32
// refine from global + u64-key (d_bits<<12 | idx) bisect -> exact, stable,
// tie-free selection. Cold exact fallback if survivors > 128.
// ---------------------------------------------------------------------------
__global__ __launch_bounds__(512) void knn_kernel(
    const float4* __restrict__ space,   // [N_TOT] f32 coords
    const float*  __restrict__ prop,    // [N_TOT * PROP_D]
    float*        __restrict__ out)     // [N_TOT * 2*PROP_D]
{
  const int lane = threadIdx.x & 63;
  const int wid  = threadIdx.x >> 6;              // 0..7
  const int row  = (int)blockIdx.x * 8 + wid;     // 1 wave = 1 row
  const int m0   = row & ~(M_EV - 1);
  const int mloc = row & (M_EV - 1);

  __shared__ uint4 s_pk[M_EV / 2];                // 32 KB pair-packed f16
  __shared__ int   s_ci[8][CAND_CAP];             // 4 KB survivor indices
  __shared__ uint2 s_w[8][K_NN];                  // 2 KB winners {idx, wbits}
  __shared__ int   s_cnt[8];

  // stage: pack pairs (i, i+2048) as f16x2 per dim
  {
    const float4* src = space + m0;
    #pragma unroll
    for (int it = 0; it < 4; ++it) {
      const int i = (int)threadIdx.x + it * 512;
      const float4 a = src[i];
      const float4 b = src[i + 2048];
      s_pk[i] = make_uint4(
        __builtin_bit_cast(unsigned, pkrtz(a.x, b.x)),
        __builtin_bit_cast(unsigned, pkrtz(a.y, b.y)),
        __builtin_bit_cast(unsigned, pkrtz(a.z, b.z)),
        __builtin_bit_cast(unsigned, pkrtz(a.w, b.w)));
    }
  }
  if (lane == 0) s_cnt[wid] = 0;
  __syncthreads();

  // query coords: exact f32 (for refine) + duplicated f16 packs
  const float4 qf = space[m0 + mloc];
  const h2 qx = pkrtz(qf.x, qf.x), qy = pkrtz(qf.y, qf.y);
  const h2 qz = pkrtz(qf.z, qf.z), qw = pkrtz(qf.w, qf.w);

  // packed approx distance for candidate pair (t*64+lane, +2048)
  auto pdist = [&](int t) -> h2 {
    const uint4 u = s_pk[lane + (t << 6)];
    const h2 dx = qx - __builtin_bit_cast(h2, u.x);
    const h2 dy = qy - __builtin_bit_cast(h2, u.y);
    const h2 dz = qz - __builtin_bit_cast(h2, u.z);
    const h2 dw = qw - __builtin_bit_cast(h2, u.w);
    h2 s = dx * dx;
    s = dy * dy + s;
    s = dz * dz + s;
    s = dw * dw + s;
    return s;
  };

  // --- pass A: packed running per-lane min (128 partitions) ---
  h2 mn; mn.x = (_Float16)65504.f; mn.y = (_Float16)65504.f;
  #pragma unroll
  for (int t = 0; t < 32; ++t) mn = pkmin(mn, pdist(t));

  const float mn0 = (float)mn.x, mn1 = (float)mn.y;

  // --- Tub = 32nd smallest of the 128 partition mins (bit-bisect) ---
  unsigned blo = 0u, bhi = 0x477FE000u;           // [0, 65504]
  while (blo < bhi) {
    const unsigned mid = (blo + bhi) >> 1;
    const float fm = __uint_as_float(mid);
    const int c = (int)__popcll(__ballot(mn0 <= fm)) +
                  (int)__popcll(__ballot(mn1 <= fm));
    if (c >= K_NN) { bhi = mid; if (c == K_NN) break; }
    else blo = mid + 1;
  }
  const float T = __uint_as_float(bhi) + MARGIN;  // safe prune threshold

  // --- pass B: recompute (bit-identical) + LDS-atomic append of indices ---
  #pragma unroll
  for (int t = 0; t < 32; ++t) {
    const h2 s = pdist(t);
    const float e0 = (float)s.x, e1 = (float)s.y;
    if (e0 <= T) {
      const int pos = atomicAdd(&s_cnt[wid], 1);
      if (pos < CAND_CAP) s_ci[wid][pos] = (t << 6) + lane;
    }
    if (e1 <= T) {
      const int pos = atomicAdd(&s_cnt[wid], 1);
      if (pos < CAND_CAP) s_ci[wid][pos] = (t << 6) + lane + 2048;
    }
  }
  int C = s_cnt[wid];

  if (C > CAND_CAP) {
    // --- cold exact fallback: bisect exact f32 d from global, fill top-32 ---
    const float4* __restrict__ ev = space + m0;
    unsigned lo = 0u, hi = __float_as_uint(T);
    while (lo < hi) {
      const unsigned mid = (lo + hi) >> 1;
      const float fm = __uint_as_float(mid);
      int c = 0;
      #pragma unroll 1
      for (int t = 0; t < 64; ++t) {
        const float4 cc = ev[lane + (t << 6)];
        const float dx = qf.x - cc.x, dy = qf.y - cc.y;
        const float dz = qf.z - cc.z, dw = qf.w - cc.w;
        const float dd = fmaf(dx, dx, fmaf(dy, dy, fmaf(dz, dz, dw * dw)));
        c += (int)__popcll(__ballot(dd <= fm));
      }
      if (c >= K_NN) { hi = mid; if (c == K_NN) break; }
      else lo = mid + 1;
    }
    const float Tf = __uint_as_float(hi);
    int cnt = 0;
    #pragma unroll 1
    for (int pass = 0; pass < 2; ++pass) {        // 0: strict-less, 1: equal
      #pragma unroll 1
      for (int t = 0; t < 64; ++t) {
        const float4 cc = ev[lane + (t << 6)];
        const float dx = qf.x - cc.x, dy = qf.y - cc.y;
        const float dz = qf.z - cc.z, dw = qf.w - cc.w;
        const float dd = fmaf(dx, dx, fmaf(dy, dy, fmaf(dz, dz, dw * dw)));
        const bool p = pass ? (dd == Tf) : (dd < Tf);
        const u64 mk = __ballot(p);
        if (p) {
          const int pos = cnt + mbcnt64(mk);
          if (pos < K_NN) s_ci[wid][pos] = (t << 6) + lane;
        }
        cnt += (int)__popcll(mk);
      }
      if (cnt >= K_NN) break;
    }
    C = K_NN;
  }

  // --- refine: exact f32 distances for <=2 survivors/lane (global, L2) ---
  const bool h0 = (lane < C), h1 = (64 + lane < C);
  const int i0 = h0 ? s_ci[wid][lane]      : 0;
  const int i1 = h1 ? s_ci[wid][64 + lane] : 0;
  float v0 = INFINITY, v1 = INFINITY;
  if (h0) {
    const float4 cc = space[m0 + i0];
    const float dx = qf.x - cc.x, dy = qf.y - cc.y;
    const float dz = qf.z - cc.z, dw = qf.w - cc.w;
    v0 = fmaf(dx, dx, fmaf(dy, dy, fmaf(dz, dz, dw * dw)));
  }
  if (h1) {
    const float4 cc = space[m0 + i1];
    const float dx = qf.x - cc.x, dy = qf.y - cc.y;
    const float dz = qf.z - cc.z, dw = qf.w - cc.w;
    v1 = fmaf(dx, dx, fmaf(dy, dy, fmaf(dz, dz, dw * dw)));
  }

  // --- u64-key exact top-32: key = d_bits<<12 | idx (unique -> tie-free) ---
  const u64 k0 = h0 ? (((u64)__float_as_uint(v0) << 12) | (unsigned)i0) : ~0ull;
  const u64 k1 = h1 ? (((u64)__float_as_uint(v1) << 12) | (unsigned)i1) : ~0ull;

  u64 klo = 0ull;
  u64 khi = (((u64)__float_as_uint(T * 1.01f + 0.02f)) << 12) | 0xFFFull;
  {
    const int c0 = (int)__popcll(__ballot(k0 <= khi)) +
                   (int)__popcll(__ballot(k1 <= khi));
    if (c0 < K_NN) khi = ((u64)0x7F800000ull << 12);  // safety net
  }
  while (klo < khi) {
    const u64 mid = (klo + khi) >> 1;
    const int c = (int)__popcll(__ballot(k0 <= mid)) +
                  (int)__popcll(__ballot(k1 <= mid));
    if (c >= K_NN) { khi = mid; if (c == K_NN) break; }
    else klo = mid + 1;
  }
  const u64 Kstar = khi;                          // 32nd-smallest key

  const bool sel0 = (k0 <= Kstar), sel1 = (k1 <= Kstar);  // exactly 32
  {
    const u64 mkS0 = __ballot(sel0);
    if (sel0) {
      const int pos = mbcnt64(mkS0);
      s_w[wid][pos] = make_uint2((unsigned)i0, __float_as_uint(__expf(-10.f * v0)));
    }
    const int b0 = (int)__popcll(mkS0);
    const u64 mkS1 = __ballot(sel1);
    if (sel1) {
      const int pos = b0 + mbcnt64(mkS1);
      s_w[wid][pos] = make_uint2((unsigned)i1, __float_as_uint(__expf(-10.f * v1)));
    }
  }

  // --- aggregation: lane = feature, 32 winners ---
  float accm = 0.f;
  float accx = -INFINITY;
  const float* __restrict__ pb = prop + ((size_t)m0 << 6) + lane;
  #pragma unroll 8
  for (int n = 0; n < K_NN; ++n) {
    const uint2 wn = s_w[wid][n];                 // uniform LDS broadcast
    const float w = __uint_as_float(wn.y);
    const float v = pb[(size_t)wn.x << 6];        // coalesced 256B, L2-hot
    const float wv = w * v;
    accm += wv;
    accx = fmaxf(accx, wv);
  }
  out[(size_t)row * 128 + lane]      = accm * (1.f / K_NN);
  out[(size_t)row * 128 + 64 + lane] = accx;
}

// ---------------------------------------------------------------------------
extern "C" void kernel_launch(void* const* d_in, const int* in_sizes, int n_in,
                              void* d_out, int out_size, void* d_ws, size_t ws_size,
                              hipStream_t stream) {
  const float* x  = (const float*)d_in[0];
  const float* Ws = (const float*)d_in[1];
  const float* bs = (const float*)d_in[2];
  const float* Wp = (const float*)d_in[3];
  const float* bp = (const float*)d_in[4];
  float* out = (float*)d_out;

  // workspace layout: prop [N,64] f32 (4 MB) | space [N,4] f32 (256 KB)
  float* prop  = (float*)d_ws;
  float* space = (float*)((char*)d_ws + (size_t)N_TOT * PROP_D * sizeof(float));

  linear_kernel<<<N_TOT / 16, 256, 0, stream>>>(x, Ws, bs, Wp, bp, space, prop);
  knn_kernel<<<N_TOT / 8, 512, 0, stream>>>((const float4*)space, prop, out);
}

// Round 8
// 54.871 us; speedup vs baseline: 2.2997x; 1.1233x over previous
//
#include <hip/hip_runtime.h>
#include <hip/hip_bf16.h>
#include <math.h>

#define N_TOT   16384
#define M_EV    4096
#define IN_DIM  128
#define SPACE_D 4
#define PROP_D  64
#define K_NN    32
#define CAND_CAP 128            // survivor slots per row (2/lane)
#define MARGIN  0.04f           // covers f16 approx error near threshold

typedef _Float16 h2 __attribute__((ext_vector_type(2)));
typedef unsigned long long u64;

__device__ __forceinline__ h2 pkmin(h2 a, h2 b) {
#if __has_builtin(__builtin_elementwise_min)
  return __builtin_elementwise_min(a, b);
#else
  h2 r; r.x = (a.x < b.x) ? a.x : b.x; r.y = (a.y < b.y) ? a.y : b.y; return r;
#endif
}

__device__ __forceinline__ h2 pkrtz(float a, float b) {
  return __builtin_bit_cast(h2, __builtin_amdgcn_cvt_pkrtz(a, b));
}

// ---------------------------------------------------------------------------
// Kernel 1: space = x @ Ws + bs ; prop = x @ Wp + bp
// ---------------------------------------------------------------------------
__global__ __launch_bounds__(256) void linear_kernel(
    const float* __restrict__ x,
    const float* __restrict__ Ws, const float* __restrict__ bs,
    const float* __restrict__ Wp, const float* __restrict__ bp,
    float* __restrict__ space, float* __restrict__ prop)
{
  const int lane = threadIdx.x & 63;
  const int wid  = threadIdx.x >> 6;
  const int r0   = __builtin_amdgcn_readfirstlane((int)blockIdx.x * 16 + wid * 4);

  const float* xr = x + (size_t)r0 * IN_DIM;

  float a0 = bp[lane];
  float a1 = a0, a2 = a0, a3 = a0;
  #pragma unroll
  for (int i = 0; i < IN_DIM; ++i) {
    const float w = Wp[i * PROP_D + lane];
    a0 = fmaf(xr[i],              w, a0);
    a1 = fmaf(xr[IN_DIM + i],     w, a1);
    a2 = fmaf(xr[2 * IN_DIM + i], w, a2);
    a3 = fmaf(xr[3 * IN_DIM + i], w, a3);
  }
  prop[(size_t)(r0 + 0) * PROP_D + lane] = a0;
  prop[(size_t)(r0 + 1) * PROP_D + lane] = a1;
  prop[(size_t)(r0 + 2) * PROP_D + lane] = a2;
  prop[(size_t)(r0 + 3) * PROP_D + lane] = a3;

  if (lane < 16) {
    const int r = lane >> 2, c = lane & 3;
    const float* xq = x + (size_t)(r0 + r) * IN_DIM;
    float a = bs[c];
    #pragma unroll
    for (int i = 0; i < IN_DIM; ++i)
      a = fmaf(xq[i], Ws[i * SPACE_D + c], a);
    space[(size_t)(r0 + r) * SPACE_D + c] = a;
  }
}

// per-lane count of set bits of mk strictly below this lane
__device__ __forceinline__ int mbcnt64(u64 mk) {
  return (int)__builtin_amdgcn_mbcnt_hi((unsigned)(mk >> 32),
           __builtin_amdgcn_mbcnt_lo((unsigned)mk, 0u));
}

// ---------------------------------------------------------------------------
// Kernel 2: per-row exact KNN (K=32 of 4096) + weighted aggregation.
// 512 threads = 8 waves = 8 rows. Slab pair-packed f16 in LDS (32 KB).
// Pass A computes all 4096 approx distances ONCE, keeping them in 32 packed
// h2 VGPRs (2 cands/reg), plus a running packed lane-min. Tub via ballot-
// bisect on the 128 partition mins; T = Tub + MARGIN. Pass B is register-only:
// 2 f16 compares + LDS-atomic append per step (no LDS reads, no recompute).
// Tail: exact f32 refine from global + u64-key (d_bits<<12 | idx) bisect ->
// exact, stable, tie-free selection. Cold exact fallback if survivors > 128.
// ---------------------------------------------------------------------------
__global__ __launch_bounds__(512) void knn_kernel(
    const float4* __restrict__ space,   // [N_TOT] f32 coords
    const float*  __restrict__ prop,    // [N_TOT * PROP_D]
    float*        __restrict__ out)     // [N_TOT * 2*PROP_D]
{
  const int lane = threadIdx.x & 63;
  const int wid  = threadIdx.x >> 6;              // 0..7
  const int row  = (int)blockIdx.x * 8 + wid;     // 1 wave = 1 row
  const int m0   = row & ~(M_EV - 1);
  const int mloc = row & (M_EV - 1);

  __shared__ uint4 s_pk[M_EV / 2];                // 32 KB pair-packed f16
  __shared__ int   s_ci[8][CAND_CAP];             // 4 KB survivor indices
  __shared__ uint2 s_w[8][K_NN];                  // 2 KB winners {idx, wbits}
  __shared__ int   s_cnt[8];

  // stage: pack pairs (i, i+2048) as f16x2 per dim
  {
    const float4* src = space + m0;
    #pragma unroll
    for (int it = 0; it < 4; ++it) {
      const int i = (int)threadIdx.x + it * 512;
      const float4 a = src[i];
      const float4 b = src[i + 2048];
      s_pk[i] = make_uint4(
        __builtin_bit_cast(unsigned, pkrtz(a.x, b.x)),
        __builtin_bit_cast(unsigned, pkrtz(a.y, b.y)),
        __builtin_bit_cast(unsigned, pkrtz(a.z, b.z)),
        __builtin_bit_cast(unsigned, pkrtz(a.w, b.w)));
    }
  }
  if (lane == 0) s_cnt[wid] = 0;
  __syncthreads();

  // query coords: exact f32 (for refine) + duplicated f16 packs
  const float4 qf = space[m0 + mloc];
  const h2 qx = pkrtz(qf.x, qf.x), qy = pkrtz(qf.y, qf.y);
  const h2 qz = pkrtz(qf.z, qf.z), qw = pkrtz(qf.w, qf.w);

  // --- pass A: packed distances -> 32 registers + running packed min ---
  unsigned pd[32];
  h2 mn; mn.x = (_Float16)65504.f; mn.y = (_Float16)65504.f;
  #pragma unroll
  for (int t = 0; t < 32; ++t) {
    const uint4 u = s_pk[lane + (t << 6)];
    const h2 dx = qx - __builtin_bit_cast(h2, u.x);
    const h2 dy = qy - __builtin_bit_cast(h2, u.y);
    const h2 dz = qz - __builtin_bit_cast(h2, u.z);
    const h2 dw = qw - __builtin_bit_cast(h2, u.w);
    h2 s = dx * dx;
    s = dy * dy + s;
    s = dz * dz + s;
    s = dw * dw + s;
    pd[t] = __builtin_bit_cast(unsigned, s);
    mn = pkmin(mn, s);
  }

  const float mn0 = (float)mn.x, mn1 = (float)mn.y;

  // --- Tub = 32nd smallest of the 128 partition mins (bit-bisect) ---
  unsigned blo = 0u, bhi = 0x477FE000u;           // [0, 65504]
  while (blo < bhi) {
    const unsigned mid = (blo + bhi) >> 1;
    const float fm = __uint_as_float(mid);
    const int c = (int)__popcll(__ballot(mn0 <= fm)) +
                  (int)__popcll(__ballot(mn1 <= fm));
    if (c >= K_NN) { bhi = mid; if (c == K_NN) break; }
    else blo = mid + 1;
  }
  const float T = __uint_as_float(bhi) + MARGIN;  // safe prune threshold
  const h2 Th = pkrtz(T, T);                      // RTZ error << MARGIN

  // --- pass B: register-only compares + LDS-atomic append of indices ---
  #pragma unroll
  for (int t = 0; t < 32; ++t) {
    const h2 s = __builtin_bit_cast(h2, pd[t]);
    if (s.x <= Th.x) {
      const int pos = atomicAdd(&s_cnt[wid], 1);
      if (pos < CAND_CAP) s_ci[wid][pos] = (t << 6) + lane;
    }
    if (s.y <= Th.y) {
      const int pos = atomicAdd(&s_cnt[wid], 1);
      if (pos < CAND_CAP) s_ci[wid][pos] = (t << 6) + lane + 2048;
    }
  }
  int C = s_cnt[wid];

  if (C > CAND_CAP) {
    // --- cold exact fallback: bisect exact f32 d from global, fill top-32 ---
    const float4* __restrict__ ev = space + m0;
    unsigned lo = 0u, hi = __float_as_uint(T);
    while (lo < hi) {
      const unsigned mid = (lo + hi) >> 1;
      const float fm = __uint_as_float(mid);
      int c = 0;
      #pragma unroll 1
      for (int t = 0; t < 64; ++t) {
        const float4 cc = ev[lane + (t << 6)];
        const float dx = qf.x - cc.x, dy = qf.y - cc.y;
        const float dz = qf.z - cc.z, dw = qf.w - cc.w;
        const float dd = fmaf(dx, dx, fmaf(dy, dy, fmaf(dz, dz, dw * dw)));
        c += (int)__popcll(__ballot(dd <= fm));
      }
      if (c >= K_NN) { hi = mid; if (c == K_NN) break; }
      else lo = mid + 1;
    }
    const float Tf = __uint_as_float(hi);
    int cnt = 0;
    #pragma unroll 1
    for (int pass = 0; pass < 2; ++pass) {        // 0: strict-less, 1: equal
      #pragma unroll 1
      for (int t = 0; t < 64; ++t) {
        const float4 cc = ev[lane + (t << 6)];
        const float dx = qf.x - cc.x, dy = qf.y - cc.y;
        const float dz = qf.z - cc.z, dw = qf.w - cc.w;
        const float dd = fmaf(dx, dx, fmaf(dy, dy, fmaf(dz, dz, dw * dw)));
        const bool p = pass ? (dd == Tf) : (dd < Tf);
        const u64 mk = __ballot(p);
        if (p) {
          const int pos = cnt + mbcnt64(mk);
          if (pos < K_NN) s_ci[wid][pos] = (t << 6) + lane;
        }
        cnt += (int)__popcll(mk);
      }
      if (cnt >= K_NN) break;
    }
    C = K_NN;
  }

  // --- refine: exact f32 distances for <=2 survivors/lane (global, L2) ---
  const bool h0 = (lane < C), h1 = (64 + lane < C);
  const int i0 = h0 ? s_ci[wid][lane]      : 0;
  const int i1 = h1 ? s_ci[wid][64 + lane] : 0;
  float v0 = INFINITY, v1 = INFINITY;
  if (h0) {
    const float4 cc = space[m0 + i0];
    const float dx = qf.x - cc.x, dy = qf.y - cc.y;
    const float dz = qf.z - cc.z, dw = qf.w - cc.w;
    v0 = fmaf(dx, dx, fmaf(dy, dy, fmaf(dz, dz, dw * dw)));
  }
  if (h1) {
    const float4 cc = space[m0 + i1];
    const float dx = qf.x - cc.x, dy = qf.y - cc.y;
    const float dz = qf.z - cc.z, dw = qf.w - cc.w;
    v1 = fmaf(dx, dx, fmaf(dy, dy, fmaf(dz, dz, dw * dw)));
  }

  // --- u64-key exact top-32: key = d_bits<<12 | idx (unique -> tie-free) ---
  const u64 k0 = h0 ? (((u64)__float_as_uint(v0) << 12) | (unsigned)i0) : ~0ull;
  const u64 k1 = h1 ? (((u64)__float_as_uint(v1) << 12) | (unsigned)i1) : ~0ull;

  u64 klo = 0ull;
  u64 khi = (((u64)__float_as_uint(T * 1.01f + 0.02f)) << 12) | 0xFFFull;
  {
    const int c0 = (int)__popcll(__ballot(k0 <= khi)) +
                   (int)__popcll(__ballot(k1 <= khi));
    if (c0 < K_NN) khi = ((u64)0x7F800000ull << 12);  // safety net
  }
  while (klo < khi) {
    const u64 mid = (klo + khi) >> 1;
    const int c = (int)__popcll(__ballot(k0 <= mid)) +
                  (int)__popcll(__ballot(k1 <= mid));
    if (c >= K_NN) { khi = mid; if (c == K_NN) break; }
    else klo = mid + 1;
  }
  const u64 Kstar = khi;                          // 32nd-smallest key

  const bool sel0 = (k0 <= Kstar), sel1 = (k1 <= Kstar);  // exactly 32
  {
    const u64 mkS0 = __ballot(sel0);
    if (sel0) {
      const int pos = mbcnt64(mkS0);
      s_w[wid][pos] = make_uint2((unsigned)i0, __float_as_uint(__expf(-10.f * v0)));
    }
    const int b0 = (int)__popcll(mkS0);
    const u64 mkS1 = __ballot(sel1);
    if (sel1) {
      const int pos = b0 + mbcnt64(mkS1);
      s_w[wid][pos] = make_uint2((unsigned)i1, __float_as_uint(__expf(-10.f * v1)));
    }
  }

  // --- aggregation: lane = feature, 32 winners ---
  float accm = 0.f;
  float accx = -INFINITY;
  const float* __restrict__ pb = prop + ((size_t)m0 << 6) + lane;
  #pragma unroll 8
  for (int n = 0; n < K_NN; ++n) {
    const uint2 wn = s_w[wid][n];                 // uniform LDS broadcast
    const float w = __uint_as_float(wn.y);
    const float v = pb[(size_t)wn.x << 6];        // coalesced 256B, L2-hot
    const float wv = w * v;
    accm += wv;
    accx = fmaxf(accx, wv);
  }
  out[(size_t)row * 128 + lane]      = accm * (1.f / K_NN);
  out[(size_t)row * 128 + 64 + lane] = accx;
}

// ---------------------------------------------------------------------------
extern "C" void kernel_launch(void* const* d_in, const int* in_sizes, int n_in,
                              void* d_out, int out_size, void* d_ws, size_t ws_size,
                              hipStream_t stream) {
  const float* x  = (const float*)d_in[0];
  const float* Ws = (const float*)d_in[1];
  const float* bs = (const float*)d_in[2];
  const float* Wp = (const float*)d_in[3];
  const float* bp = (const float*)d_in[4];
  float* out = (float*)d_out;

  // workspace layout: prop [N,64] f32 (4 MB) | space [N,4] f32 (256 KB)
  float* prop  = (float*)d_ws;
  float* space = (float*)((char*)d_ws + (size_t)N_TOT * PROP_D * sizeof(float));

  linear_kernel<<<N_TOT / 16, 256, 0, stream>>>(x, Ws, bs, Wp, bp, space, prop);
  knn_kernel<<<N_TOT / 8, 512, 0, stream>>>((const float4*)space, prop, out);
}

// Round 9
// 52.992 us; speedup vs baseline: 2.3813x; 1.0355x over previous
//
#include <hip/hip_runtime.h>
#include <hip/hip_bf16.h>
#include <math.h>

#define N_TOT   16384
#define M_EV    4096
#define IN_DIM  128
#define SPACE_D 4
#define PROP_D  64
#define K_NN    32
#define CAND_CAP 128            // survivor slots per row (2/lane)
#define MARGIN  0.04f           // covers f16 approx error near threshold (>= 2*err)

typedef _Float16 h2 __attribute__((ext_vector_type(2)));
typedef unsigned long long u64;

__device__ __forceinline__ h2 pkmin(h2 a, h2 b) {
#if __has_builtin(__builtin_elementwise_min)
  return __builtin_elementwise_min(a, b);
#else
  h2 r; r.x = (a.x < b.x) ? a.x : b.x; r.y = (a.y < b.y) ? a.y : b.y; return r;
#endif
}

__device__ __forceinline__ h2 pkrtz(float a, float b) {
  return __builtin_bit_cast(h2, __builtin_amdgcn_cvt_pkrtz(a, b));
}

// ---------------------------------------------------------------------------
// Kernel 1: space = x @ Ws + bs ; prop = x @ Wp + bp
// ---------------------------------------------------------------------------
__global__ __launch_bounds__(256) void linear_kernel(
    const float* __restrict__ x,
    const float* __restrict__ Ws, const float* __restrict__ bs,
    const float* __restrict__ Wp, const float* __restrict__ bp,
    float* __restrict__ space, float* __restrict__ prop)
{
  const int lane = threadIdx.x & 63;
  const int wid  = threadIdx.x >> 6;
  const int r0   = __builtin_amdgcn_readfirstlane((int)blockIdx.x * 16 + wid * 4);

  const float* xr = x + (size_t)r0 * IN_DIM;

  float a0 = bp[lane];
  float a1 = a0, a2 = a0, a3 = a0;
  #pragma unroll
  for (int i = 0; i < IN_DIM; ++i) {
    const float w = Wp[i * PROP_D + lane];
    a0 = fmaf(xr[i],              w, a0);
    a1 = fmaf(xr[IN_DIM + i],     w, a1);
    a2 = fmaf(xr[2 * IN_DIM + i], w, a2);
    a3 = fmaf(xr[3 * IN_DIM + i], w, a3);
  }
  prop[(size_t)(r0 + 0) * PROP_D + lane] = a0;
  prop[(size_t)(r0 + 1) * PROP_D + lane] = a1;
  prop[(size_t)(r0 + 2) * PROP_D + lane] = a2;
  prop[(size_t)(r0 + 3) * PROP_D + lane] = a3;

  if (lane < 16) {
    const int r = lane >> 2, c = lane & 3;
    const float* xq = x + (size_t)(r0 + r) * IN_DIM;
    float a = bs[c];
    #pragma unroll
    for (int i = 0; i < IN_DIM; ++i)
      a = fmaf(xq[i], Ws[i * SPACE_D + c], a);
    space[(size_t)(r0 + r) * SPACE_D + c] = a;
  }
}

// per-lane count of set bits of mk strictly below this lane
__device__ __forceinline__ int mbcnt64(u64 mk) {
  return (int)__builtin_amdgcn_mbcnt_hi((unsigned)(mk >> 32),
           __builtin_amdgcn_mbcnt_lo((unsigned)mk, 0u));
}

// ---------------------------------------------------------------------------
// Kernel 2: per-row exact KNN (K=32 of 4096) + weighted aggregation.
// 512 threads = 8 waves = 8 rows. Slab pair-packed f16 in LDS (32 KB).
// Pass A: all 4096 approx distances once -> 32 packed h2 VGPRs (kept live via
// asm + launch_bounds(512,8); LDS caps occupancy so VGPRs are free) + packed
// lane-min. Tub: 15-iter integer bisect on f16 CODE space of the 128 partition
// mins. Pass B: register-only f16 compares + LDS-atomic append of indices.
// Refine: exact f32 from global for <=2 survivors/lane. Tail: f32-bits bisect
// (early exit) + stable lowest-index tie select (exact = JAX semantics).
// Cold exact fallback if survivors > 128.
// ---------------------------------------------------------------------------
__global__ __launch_bounds__(512, 8) void knn_kernel(
    const float4* __restrict__ space,   // [N_TOT] f32 coords
    const float*  __restrict__ prop,    // [N_TOT * PROP_D]
    float*        __restrict__ out)     // [N_TOT * 2*PROP_D]
{
  const int lane = threadIdx.x & 63;
  const int wid  = threadIdx.x >> 6;              // 0..7
  const int row  = (int)blockIdx.x * 8 + wid;     // 1 wave = 1 row
  const int m0   = row & ~(M_EV - 1);
  const int mloc = row & (M_EV - 1);

  __shared__ uint4 s_pk[M_EV / 2];                // 32 KB pair-packed f16
  __shared__ int   s_ci[8][CAND_CAP];             // 4 KB survivor indices
  __shared__ uint2 s_w[8][K_NN];                  // 2 KB winners {idx, wbits}
  __shared__ int   s_cnt[8];

  // stage: pack pairs (i, i+2048) as f16x2 per dim
  {
    const float4* src = space + m0;
    #pragma unroll
    for (int it = 0; it < 4; ++it) {
      const int i = (int)threadIdx.x + it * 512;
      const float4 a = src[i];
      const float4 b = src[i + 2048];
      s_pk[i] = make_uint4(
        __builtin_bit_cast(unsigned, pkrtz(a.x, b.x)),
        __builtin_bit_cast(unsigned, pkrtz(a.y, b.y)),
        __builtin_bit_cast(unsigned, pkrtz(a.z, b.z)),
        __builtin_bit_cast(unsigned, pkrtz(a.w, b.w)));
    }
  }
  if (lane == 0) s_cnt[wid] = 0;
  __syncthreads();

  // query coords: exact f32 (for refine) + duplicated f16 packs
  const float4 qf = space[m0 + mloc];
  const h2 qx = pkrtz(qf.x, qf.x), qy = pkrtz(qf.y, qf.y);
  const h2 qz = pkrtz(qf.z, qf.z), qw = pkrtz(qf.w, qf.w);

  // --- pass A: packed distances -> 32 registers + running packed min ---
  unsigned pd[32];
  h2 mn; mn.x = (_Float16)65504.f; mn.y = (_Float16)65504.f;
  #pragma unroll
  for (int t = 0; t < 32; ++t) {
    const uint4 u = s_pk[lane + (t << 6)];
    const h2 dx = qx - __builtin_bit_cast(h2, u.x);
    const h2 dy = qy - __builtin_bit_cast(h2, u.y);
    const h2 dz = qz - __builtin_bit_cast(h2, u.z);
    const h2 dw = qw - __builtin_bit_cast(h2, u.w);
    h2 s = dx * dx;
    s = dy * dy + s;
    s = dz * dz + s;
    s = dw * dw + s;
    pd[t] = __builtin_bit_cast(unsigned, s);
    mn = pkmin(mn, s);
  }

  // --- Tub: 32nd smallest of 128 partition mins, bisect on f16 CODE space ---
  // nonneg f16: integer code order == value order; <=15 iterations.
  const unsigned mnbits = __builtin_bit_cast(unsigned, mn);
  const unsigned c0 = mnbits & 0xFFFFu, c1 = mnbits >> 16;
  unsigned blo = 0u, bhi = 0x7C00u;
  while (blo < bhi) {
    const unsigned mid = (blo + bhi) >> 1;
    const int c = (int)__popcll(__ballot(c0 <= mid)) +
                  (int)__popcll(__ballot(c1 <= mid));
    if (c >= K_NN) { bhi = mid; if (c == K_NN) break; }
    else blo = mid + 1;
  }
  const float T = (float)__builtin_bit_cast(_Float16, (unsigned short)bhi) + MARGIN;
  const h2 Th = pkrtz(T, T);                      // RTZ error << MARGIN

  // keep pass-A distances live (defeat remat-from-LDS in pass B)
  #pragma unroll
  for (int t = 0; t < 32; ++t) asm volatile("" : "+v"(pd[t]));

  // --- pass B: register-only compares + LDS-atomic append of indices ---
  #pragma unroll
  for (int t = 0; t < 32; ++t) {
    const h2 s = __builtin_bit_cast(h2, pd[t]);
    if (s.x <= Th.x) {
      const int pos = atomicAdd(&s_cnt[wid], 1);
      if (pos < CAND_CAP) s_ci[wid][pos] = (t << 6) + lane;
    }
    if (s.y <= Th.y) {
      const int pos = atomicAdd(&s_cnt[wid], 1);
      if (pos < CAND_CAP) s_ci[wid][pos] = (t << 6) + lane + 2048;
    }
  }
  int C = s_cnt[wid];

  if (C > CAND_CAP) {
    // --- cold exact fallback: bisect exact f32 d from global, fill top-32 ---
    const float4* __restrict__ ev = space + m0;
    unsigned lo = 0u, hi = __float_as_uint(T);
    while (lo < hi) {
      const unsigned mid = (lo + hi) >> 1;
      const float fm = __uint_as_float(mid);
      int c = 0;
      #pragma unroll 1
      for (int t = 0; t < 64; ++t) {
        const float4 cc = ev[lane + (t << 6)];
        const float dx = qf.x - cc.x, dy = qf.y - cc.y;
        const float dz = qf.z - cc.z, dw = qf.w - cc.w;
        const float dd = fmaf(dx, dx, fmaf(dy, dy, fmaf(dz, dz, dw * dw)));
        c += (int)__popcll(__ballot(dd <= fm));
      }
      if (c >= K_NN) { hi = mid; if (c == K_NN) break; }
      else lo = mid + 1;
    }
    const float Tf = __uint_as_float(hi);
    int cnt = 0;
    #pragma unroll 1
    for (int pass = 0; pass < 2; ++pass) {        // 0: strict-less, 1: equal
      #pragma unroll 1
      for (int t = 0; t < 64; ++t) {
        const float4 cc = ev[lane + (t << 6)];
        const float dx = qf.x - cc.x, dy = qf.y - cc.y;
        const float dz = qf.z - cc.z, dw = qf.w - cc.w;
        const float dd = fmaf(dx, dx, fmaf(dy, dy, fmaf(dz, dz, dw * dw)));
        const bool p = pass ? (dd == Tf) : (dd < Tf);
        const u64 mk = __ballot(p);
        if (p) {
          const int pos = cnt + mbcnt64(mk);
          if (pos < K_NN) s_ci[wid][pos] = (t << 6) + lane;
        }
        cnt += (int)__popcll(mk);
      }
      if (cnt >= K_NN) break;
    }
    C = K_NN;
  }

  // --- refine: exact f32 distances for <=2 survivors/lane (global, L2) ---
  const bool h0 = (lane < C), h1 = (64 + lane < C);
  const int i0 = h0 ? s_ci[wid][lane]      : 0;
  const int i1 = h1 ? s_ci[wid][64 + lane] : 0;
  float v0 = INFINITY, v1 = INFINITY;
  if (h0) {
    const float4 cc = space[m0 + i0];
    const float dx = qf.x - cc.x, dy = qf.y - cc.y;
    const float dz = qf.z - cc.z, dw = qf.w - cc.w;
    v0 = fmaf(dx, dx, fmaf(dy, dy, fmaf(dz, dz, dw * dw)));
  }
  if (h1) {
    const float4 cc = space[m0 + i1];
    const float dx = qf.x - cc.x, dy = qf.y - cc.y;
    const float dz = qf.z - cc.z, dw = qf.w - cc.w;
    v1 = fmaf(dx, dx, fmaf(dy, dy, fmaf(dz, dz, dw * dw)));
  }

  // --- tail: f32-bits bisect (early exit at c==32) on <=2 values/lane ---
  unsigned lo = 0u, hi = __float_as_uint(T);
  while (lo < hi) {
    const unsigned mid = (lo + hi) >> 1;
    const float fm = __uint_as_float(mid);
    const int c = (int)__popcll(__ballot(v0 <= fm)) +
                  (int)__popcll(__ballot(v1 <= fm));
    if (c >= K_NN) { hi = mid; if (c == K_NN) break; }
    else lo = mid + 1;
  }
  const float T2 = __uint_as_float(hi);

  // stable selection: strict-less, then lowest-position equals (JAX order)
  const u64 mkE0 = __ballot(v0 == T2);
  const u64 mkE1 = __ballot(v1 == T2);
  const int L = (int)__popcll(__ballot(v0 < T2)) +
                (int)__popcll(__ballot(v1 < T2));
  const int e = K_NN - L;
  const int nE0 = (int)__popcll(mkE0);
  const bool sel0 = (v0 < T2) || ((v0 == T2) && (mbcnt64(mkE0) < e));
  const bool sel1 = (v1 < T2) || ((v1 == T2) && (nE0 + mbcnt64(mkE1) < e));

  const float w0 = __expf(-10.f * v0);
  const float w1 = __expf(-10.f * v1);

  {
    const u64 mkS0 = __ballot(sel0);
    if (sel0) {
      const int pos = mbcnt64(mkS0);
      s_w[wid][pos] = make_uint2((unsigned)i0, __float_as_uint(w0));
    }
    const int b0 = (int)__popcll(mkS0);
    const u64 mkS1 = __ballot(sel1);
    if (sel1) {
      const int pos = b0 + mbcnt64(mkS1);
      s_w[wid][pos] = make_uint2((unsigned)i1, __float_as_uint(w1));
    }
  }

  // --- aggregation: lane = feature, 32 winners ---
  float accm = 0.f;
  float accx = -INFINITY;
  const float* __restrict__ pb = prop + ((size_t)m0 << 6) + lane;
  #pragma unroll 8
  for (int n = 0; n < K_NN; ++n) {
    const uint2 wn = s_w[wid][n];                 // uniform LDS broadcast
    const float w = __uint_as_float(wn.y);
    const float v = pb[(size_t)wn.x << 6];        // coalesced 256B, L2-hot
    const float wv = w * v;
    accm += wv;
    accx = fmaxf(accx, wv);
  }
  out[(size_t)row * 128 + lane]      = accm * (1.f / K_NN);
  out[(size_t)row * 128 + 64 + lane] = accx;
}

// ---------------------------------------------------------------------------
extern "C" void kernel_launch(void* const* d_in, const int* in_sizes, int n_in,
                              void* d_out, int out_size, void* d_ws, size_t ws_size,
                              hipStream_t stream) {
  const float* x  = (const float*)d_in[0];
  const float* Ws = (const float*)d_in[1];
  const float* bs = (const float*)d_in[2];
  const float* Wp = (const float*)d_in[3];
  const float* bp = (const float*)d_in[4];
  float* out = (float*)d_out;

  // workspace layout: prop [N,64] f32 (4 MB) | space [N,4] f32 (256 KB)
  float* prop  = (float*)d_ws;
  float* space = (float*)((char*)d_ws + (size_t)N_TOT * PROP_D * sizeof(float));

  linear_kernel<<<N_TOT / 16, 256, 0, stream>>>(x, Ws, bs, Wp, bp, space, prop);
  knn_kernel<<<N_TOT / 8, 512, 0, stream>>>((const float4*)space, prop, out);
}